// Round 2
// baseline (593.050 us; speedup 1.0000x reference)
//
#include <hip/hip_runtime.h>
#include <hip/hip_bf16.h>

typedef __attribute__((ext_vector_type(8))) short short8;
typedef __attribute__((ext_vector_type(4))) float float4v;

// fp32 -> bf16 round-to-nearest-even (finite inputs only)
__device__ inline unsigned short f2bf(float f) {
    union { float f; unsigned int i; } c; c.f = f;
    unsigned int r = c.i + 0x7FFFu + ((c.i >> 16) & 1u);
    return (unsigned short)(r >> 16);
}

// ---------------------------------------------------------------------------
// Kernel 1: transpose encoder part of attn_w (fp32 rows 512..1535, [k][d])
// into W_t [d][k] (512 x 1024 bf16) so MFMA B-fragments are contiguous in k.
// ---------------------------------------------------------------------------
__global__ void k_transpose(const float* __restrict__ W,
                            unsigned short* __restrict__ Wt) {
    int idx = blockIdx.x * 256 + threadIdx.x;   // 65536 threads: 512 d x 128 kgroups
    int d  = idx & 511;
    int kg = idx >> 9;                          // k = kg*8 .. kg*8+7
    short8 v;
#pragma unroll
    for (int j = 0; j < 8; j++)
        v[j] = (short)f2bf(W[(size_t)(512 + kg * 8 + j) * 512 + d]); // coalesced over d
    *(short8*)(Wt + (size_t)d * 1024 + kg * 8) = v;
}

// ---------------------------------------------------------------------------
// Kernel 2: hb[b][d] = hidden[b,:] @ W[0:512, d] + bias[d]   (all fp32)
// ---------------------------------------------------------------------------
__global__ void k_hb(const float* __restrict__ hidden,
                     const float* __restrict__ W,
                     const float* __restrict__ bias,
                     float* __restrict__ hb) {
    int b = blockIdx.x, tid = threadIdx.x;
    __shared__ float h[512];
    for (int k = tid; k < 512; k += 256) h[k] = hidden[b * 512 + k];
    __syncthreads();
    int d0 = tid, d1 = tid + 256;
    float a0 = 0.f, a1 = 0.f;
    for (int k = 0; k < 512; k++) {
        float hk = h[k];
        a0 += hk * W[(size_t)k * 512 + d0];
        a1 += hk * W[(size_t)k * 512 + d1];
    }
    hb[b * 512 + d0] = a0 + bias[d0];
    hb[b * 512 + d1] = a1 + bias[d1];
}

// ---------------------------------------------------------------------------
// Kernel 3: fused GEMM(enc @ W_e) + tanh(.+hb) . v  reduction.
// Grid: (16 s-tiles of 64, 64 b). Block 256 = 4 waves.
// Wave w covers d in [w*128, (w+1)*128) (8 n-tiles), all 4 m-tiles of 16.
// mfma_f32_16x16x32_bf16; A loaded fp32 and converted in-register.
// ---------------------------------------------------------------------------
__launch_bounds__(256, 2)
__global__ void k_main(const float* __restrict__ enc,
                       const unsigned short* __restrict__ Wt,
                       const float* __restrict__ hb,
                       const float* __restrict__ vvec,
                       float* __restrict__ att) {
    const int b    = blockIdx.y;
    const int s0   = blockIdx.x * 64;
    const int tid  = threadIdx.x;
    const int wave = tid >> 6;
    const int lane = tid & 63;
    const int col  = lane & 15;   // n (B/D) or m (A) index
    const int quad = lane >> 4;   // k-group: k = quad*8 + j

    // B fragment base: W_t[d][k], d = wave*128 + nt*16 + col  (bf16)
    const unsigned short* bptr = Wt + (size_t)(wave * 128 + col) * 1024 + quad * 8;

    // A fragment bases per m-tile: enc[b, s0 + mt*16 + col, k]  (fp32)
    const float* aptr[4];
#pragma unroll
    for (int mt = 0; mt < 4; mt++) {
        int s = s0 + mt * 16 + col;
        if (s > 999) s = 999;                 // clamp: garbage rows masked at write
        aptr[mt] = enc + ((size_t)(b * 1000 + s) * 1024 + quad * 8);
    }

    float4v acc[4][8];
#pragma unroll
    for (int mt = 0; mt < 4; mt++)
#pragma unroll
        for (int nt = 0; nt < 8; nt++)
            acc[mt][nt] = float4v{0.f, 0.f, 0.f, 0.f};

    for (int k = 0; k < 1024; k += 32) {
        short8 afrag[4], bfrag[8];
#pragma unroll
        for (int mt = 0; mt < 4; mt++) {
            float4v a0 = *(const float4v*)(aptr[mt] + k);
            float4v a1 = *(const float4v*)(aptr[mt] + k + 4);
#pragma unroll
            for (int j = 0; j < 4; j++) {
                afrag[mt][j]     = (short)f2bf(a0[j]);
                afrag[mt][j + 4] = (short)f2bf(a1[j]);
            }
        }
#pragma unroll
        for (int nt = 0; nt < 8; nt++)
            bfrag[nt] = *(const short8*)(bptr + nt * 16 * 1024 + k);
#pragma unroll
        for (int mt = 0; mt < 4; mt++)
#pragma unroll
            for (int nt = 0; nt < 8; nt++)
                acc[mt][nt] = __builtin_amdgcn_mfma_f32_16x16x32_bf16(
                    afrag[mt], bfrag[nt], acc[mt][nt], 0, 0, 0);
    }

    // Epilogue: att_partial[m] += tanh(e + hb) * v  over this wave's 128 d's.
    float vv[8], hbv[8];
#pragma unroll
    for (int nt = 0; nt < 8; nt++) {
        int d = wave * 128 + nt * 16 + col;
        vv[nt]  = vvec[d];
        hbv[nt] = hb[b * 512 + d];
    }
    float rs[4][4];   // [mt][r] -> row m = mt*16 + quad*4 + r
#pragma unroll
    for (int mt = 0; mt < 4; mt++)
#pragma unroll
        for (int r = 0; r < 4; r++) rs[mt][r] = 0.f;

#pragma unroll
    for (int mt = 0; mt < 4; mt++)
#pragma unroll
        for (int nt = 0; nt < 8; nt++)
#pragma unroll
            for (int r = 0; r < 4; r++) {
                float e = acc[mt][nt][r] + hbv[nt];
                float t = 1.f - 2.f / (__expf(2.f * e) + 1.f);   // tanh
                rs[mt][r] += t * vv[nt];
            }

    // Reduce across the 16 cols (lanes differing in bits 0..3, same quad)
#pragma unroll
    for (int mt = 0; mt < 4; mt++)
#pragma unroll
        for (int r = 0; r < 4; r++) {
            float x = rs[mt][r];
            x += __shfl_xor(x, 1);
            x += __shfl_xor(x, 2);
            x += __shfl_xor(x, 4);
            x += __shfl_xor(x, 8);
            rs[mt][r] = x;
        }

    __shared__ float red[4][64];
    if (col == 0) {
#pragma unroll
        for (int mt = 0; mt < 4; mt++)
#pragma unroll
            for (int r = 0; r < 4; r++)
                red[wave][mt * 16 + quad * 4 + r] = rs[mt][r];
    }
    __syncthreads();
    if (tid < 64) {
        float sum = red[0][tid] + red[1][tid] + red[2][tid] + red[3][tid];
        int s = s0 + tid;
        if (s < 1000) att[b * 1000 + s] = sum;
    }
}

// ---------------------------------------------------------------------------
// Kernel 4: row softmax over S=1000, fp32 out.
// ---------------------------------------------------------------------------
__global__ void k_softmax(const float* __restrict__ att,
                          float* __restrict__ out) {
    int b = blockIdx.x, tid = threadIdx.x;
    __shared__ float sm[4], ss[4];
    float x[4], mx = -1e30f;
#pragma unroll
    for (int i = 0; i < 4; i++) {
        int s = tid + 256 * i;
        x[i] = (s < 1000) ? att[b * 1000 + s] : -1e30f;
        mx = fmaxf(mx, x[i]);
    }
    for (int off = 1; off < 64; off <<= 1) mx = fmaxf(mx, __shfl_xor(mx, off));
    if ((tid & 63) == 0) sm[tid >> 6] = mx;
    __syncthreads();
    mx = fmaxf(fmaxf(sm[0], sm[1]), fmaxf(sm[2], sm[3]));

    float ex[4], se = 0.f;
#pragma unroll
    for (int i = 0; i < 4; i++) {
        ex[i] = __expf(x[i] - mx);
        if (tid + 256 * i >= 1000) ex[i] = 0.f;
        se += ex[i];
    }
    for (int off = 1; off < 64; off <<= 1) se += __shfl_xor(se, off);
    if ((tid & 63) == 0) ss[tid >> 6] = se;
    __syncthreads();
    se = ss[0] + ss[1] + ss[2] + ss[3];
    float inv = 1.f / se;
#pragma unroll
    for (int i = 0; i < 4; i++) {
        int s = tid + 256 * i;
        if (s < 1000) out[b * 1000 + s] = ex[i] * inv;
    }
}

// ---------------------------------------------------------------------------
extern "C" void kernel_launch(void* const* d_in, const int* in_sizes, int n_in,
                              void* d_out, int out_size, void* d_ws, size_t ws_size,
                              hipStream_t stream) {
    const float* hidden = (const float*)d_in[0]; // [64,512]
    const float* enc    = (const float*)d_in[1]; // [64,1000,1024]
    const float* attn_w = (const float*)d_in[2]; // [1536,512]
    const float* attn_b = (const float*)d_in[3]; // [512]
    const float* v      = (const float*)d_in[4]; // [512]
    float* out = (float*)d_out;                  // [64,1000]

    char* ws = (char*)d_ws;
    unsigned short* Wt = (unsigned short*)ws;                       // 1 MB bf16
    float* hb  = (float*)(ws + (1 << 20));                          // 128 KB
    float* att = (float*)(ws + (1 << 20) + (128 << 10));            // 250 KB

    k_transpose<<<256, 256, 0, stream>>>(attn_w, Wt);
    k_hb<<<64, 256, 0, stream>>>(hidden, attn_w, attn_b, hb);
    k_main<<<dim3(16, 64), 256, 0, stream>>>(enc, Wt, hb, v, att);
    k_softmax<<<64, 256, 0, stream>>>(att, out);
}

// Round 3
// 481.333 us; speedup vs baseline: 1.2321x; 1.2321x over previous
//
#include <hip/hip_runtime.h>
#include <hip/hip_bf16.h>

typedef __attribute__((ext_vector_type(8))) short short8;
typedef __attribute__((ext_vector_type(4))) float float4v;

// fp32 -> bf16 round-to-nearest-even (finite inputs only)
__device__ inline unsigned short f2bf(float f) {
    union { float f; unsigned int i; } c; c.f = f;
    unsigned int r = c.i + 0x7FFFu + ((c.i >> 16) & 1u);
    return (unsigned short)(r >> 16);
}

// ---------------------------------------------------------------------------
// Kernel 1: transpose encoder part of attn_w (fp32 rows 512..1535, [k][d])
// into W_t [d][k] (512 x 1024 bf16) so MFMA B-fragments are contiguous in k.
// ---------------------------------------------------------------------------
__global__ void k_transpose(const float* __restrict__ W,
                            unsigned short* __restrict__ Wt) {
    int idx = blockIdx.x * 256 + threadIdx.x;   // 65536 threads: 512 d x 128 kgroups
    int d  = idx & 511;
    int kg = idx >> 9;                          // k = kg*8 .. kg*8+7
    short8 v;
#pragma unroll
    for (int j = 0; j < 8; j++)
        v[j] = (short)f2bf(W[(size_t)(512 + kg * 8 + j) * 512 + d]); // coalesced over d
    *(short8*)(Wt + (size_t)d * 1024 + kg * 8) = v;
}

// ---------------------------------------------------------------------------
// Kernel 2: hb[b][d] = hidden[b,:] @ W[0:512, d] + bias[d]   (all fp32)
// 512 threads = one per d; unroll 8 keeps 8 coalesced loads in flight.
// ---------------------------------------------------------------------------
__global__ void k_hb(const float* __restrict__ hidden,
                     const float* __restrict__ W,
                     const float* __restrict__ bias,
                     float* __restrict__ hb) {
    int b = blockIdx.x, d = threadIdx.x;   // 512 threads
    __shared__ float h[512];
    h[d] = hidden[b * 512 + d];
    __syncthreads();
    float a = 0.f;
#pragma unroll 8
    for (int k = 0; k < 512; k++)
        a += h[k] * W[(size_t)k * 512 + d];
    hb[b * 512 + d] = a + bias[d];
}

// ---------------------------------------------------------------------------
// Kernel 3: fused GEMM(enc @ W_e) + tanh(.+hb) . v  reduction.
// Grid: (16 s-tiles of 64, 64 b). Block 256 = 4 waves.
// Double-buffered LDS A-tile (fp32->bf16 on the fly); B direct from L2-hot Wt.
// Wave w covers d in [w*128,(w+1)*128) (8 n-tiles), all 4 m-tiles of 16.
// ---------------------------------------------------------------------------
__launch_bounds__(256, 2)
__global__ void k_main(const float* __restrict__ enc,
                       const unsigned short* __restrict__ Wt,
                       const float* __restrict__ hb,
                       const float* __restrict__ vvec,
                       float* __restrict__ att) {
    const int b    = blockIdx.y;
    const int s0   = blockIdx.x * 64;
    const int tid  = threadIdx.x;
    const int wave = tid >> 6;
    const int lane = tid & 63;
    const int col  = lane & 15;   // n (B) / m (A) index
    const int quad = lane >> 4;   // k-group: k = quad*8 + j

    // A-tile: 64 rows x 64 k bf16, +8 pad -> row stride 144B (2-way conflicts only)
    __shared__ unsigned short As[2][64][72];

    // Staging map: thread t -> row r = t>>2, col-quarter cq = t&3 (16 floats = 64B)
    const int r  = tid >> 2;
    const int cq = tid & 3;
    int s = s0 + r; if (s > 999) s = 999;          // dup rows masked at output
    const float* arow = enc + ((size_t)(b * 1000 + s) * 1024 + cq * 16);

    // B fragment base: W_t[d][k], d = wave*128 + nt*16 + col
    const unsigned short* bptr = Wt + (size_t)(wave * 128 + col) * 1024 + quad * 8;

    float4v acc[4][8];
#pragma unroll
    for (int mt = 0; mt < 4; mt++)
#pragma unroll
        for (int nt = 0; nt < 8; nt++)
            acc[mt][nt] = float4v{0.f, 0.f, 0.f, 0.f};

    // ---- prologue: stage chunk 0 ----
    float4v st[4];
#pragma unroll
    for (int j = 0; j < 4; j++) st[j] = *(const float4v*)(arow + j * 4);
    {
        short8 wv0, wv1;
#pragma unroll
        for (int j = 0; j < 4; j++) {
            wv0[j]     = (short)f2bf(st[0][j]);
            wv0[j + 4] = (short)f2bf(st[1][j]);
            wv1[j]     = (short)f2bf(st[2][j]);
            wv1[j + 4] = (short)f2bf(st[3][j]);
        }
        unsigned short* wp = &As[0][r][cq * 16];
        *(short8*)(wp)     = wv0;
        *(short8*)(wp + 8) = wv1;
    }
    __syncthreads();

    // ---- main K loop: 16 chunks of 64 ----
    for (int c = 0; c < 16; c++) {
        const int buf = c & 1;

        // issue next chunk's global loads before compute (latency overlap)
        if (c < 15) {
#pragma unroll
            for (int j = 0; j < 4; j++)
                st[j] = *(const float4v*)(arow + (c + 1) * 64 + j * 4);
        }

        // A fragments for both k-steps of this chunk
        short8 af[2][4];
#pragma unroll
        for (int ks = 0; ks < 2; ks++)
#pragma unroll
            for (int mt = 0; mt < 4; mt++)
                af[ks][mt] = *(const short8*)(&As[buf][mt * 16 + col][ks * 32 + quad * 8]);

#pragma unroll
        for (int ks = 0; ks < 2; ks++) {
            short8 bf[8];
#pragma unroll
            for (int nt = 0; nt < 8; nt++)
                bf[nt] = *(const short8*)(bptr + c * 64 + ks * 32 + (size_t)nt * 16 * 1024);
#pragma unroll
            for (int mt = 0; mt < 4; mt++)
#pragma unroll
                for (int nt = 0; nt < 8; nt++)
                    acc[mt][nt] = __builtin_amdgcn_mfma_f32_16x16x32_bf16(
                        af[ks][mt], bf[nt], acc[mt][nt], 0, 0, 0);
        }

        // convert + write next chunk into the other buffer
        if (c < 15) {
            short8 wv0, wv1;
#pragma unroll
            for (int j = 0; j < 4; j++) {
                wv0[j]     = (short)f2bf(st[0][j]);
                wv0[j + 4] = (short)f2bf(st[1][j]);
                wv1[j]     = (short)f2bf(st[2][j]);
                wv1[j + 4] = (short)f2bf(st[3][j]);
            }
            unsigned short* wq = &As[buf ^ 1][r][cq * 16];
            *(short8*)(wq)     = wv0;
            *(short8*)(wq + 8) = wv1;
        }
        __syncthreads();
    }

    // ---- epilogue: att_partial[m] += tanh(e + hb) * v over this wave's 128 d's
    float vv[8], hbv[8];
#pragma unroll
    for (int nt = 0; nt < 8; nt++) {
        int d = wave * 128 + nt * 16 + col;
        vv[nt]  = vvec[d];
        hbv[nt] = hb[b * 512 + d];
    }
    float rs[4][4];   // [mt][rg] -> row m = mt*16 + quad*4 + rg
#pragma unroll
    for (int mt = 0; mt < 4; mt++)
#pragma unroll
        for (int rg = 0; rg < 4; rg++) rs[mt][rg] = 0.f;

#pragma unroll
    for (int mt = 0; mt < 4; mt++)
#pragma unroll
        for (int nt = 0; nt < 8; nt++)
#pragma unroll
            for (int rg = 0; rg < 4; rg++) {
                float e = acc[mt][nt][rg] + hbv[nt];
                float t = 1.f - 2.f / (__expf(2.f * e) + 1.f);   // tanh
                rs[mt][rg] += t * vv[nt];
            }

#pragma unroll
    for (int mt = 0; mt < 4; mt++)
#pragma unroll
        for (int rg = 0; rg < 4; rg++) {
            float x = rs[mt][rg];
            x += __shfl_xor(x, 1);
            x += __shfl_xor(x, 2);
            x += __shfl_xor(x, 4);
            x += __shfl_xor(x, 8);
            rs[mt][rg] = x;
        }

    __shared__ float red[4][64];
    if (col == 0) {
#pragma unroll
        for (int mt = 0; mt < 4; mt++)
#pragma unroll
            for (int rg = 0; rg < 4; rg++)
                red[wave][mt * 16 + quad * 4 + rg] = rs[mt][rg];
    }
    __syncthreads();
    if (tid < 64) {
        float sum = red[0][tid] + red[1][tid] + red[2][tid] + red[3][tid];
        int ss = s0 + tid;
        if (ss < 1000) att[b * 1000 + ss] = sum;
    }
}

// ---------------------------------------------------------------------------
// Kernel 4: row softmax over S=1000, fp32 out.
// ---------------------------------------------------------------------------
__global__ void k_softmax(const float* __restrict__ att,
                          float* __restrict__ out) {
    int b = blockIdx.x, tid = threadIdx.x;
    __shared__ float sm[4], ss[4];
    float x[4], mx = -1e30f;
#pragma unroll
    for (int i = 0; i < 4; i++) {
        int s = tid + 256 * i;
        x[i] = (s < 1000) ? att[b * 1000 + s] : -1e30f;
        mx = fmaxf(mx, x[i]);
    }
    for (int off = 1; off < 64; off <<= 1) mx = fmaxf(mx, __shfl_xor(mx, off));
    if ((tid & 63) == 0) sm[tid >> 6] = mx;
    __syncthreads();
    mx = fmaxf(fmaxf(sm[0], sm[1]), fmaxf(sm[2], sm[3]));

    float ex[4], se = 0.f;
#pragma unroll
    for (int i = 0; i < 4; i++) {
        ex[i] = __expf(x[i] - mx);
        if (tid + 256 * i >= 1000) ex[i] = 0.f;
        se += ex[i];
    }
    for (int off = 1; off < 64; off <<= 1) se += __shfl_xor(se, off);
    if ((tid & 63) == 0) ss[tid >> 6] = se;
    __syncthreads();
    se = ss[0] + ss[1] + ss[2] + ss[3];
    float inv = 1.f / se;
#pragma unroll
    for (int i = 0; i < 4; i++) {
        int s = tid + 256 * i;
        if (s < 1000) out[b * 1000 + s] = ex[i] * inv;
    }
}

// ---------------------------------------------------------------------------
extern "C" void kernel_launch(void* const* d_in, const int* in_sizes, int n_in,
                              void* d_out, int out_size, void* d_ws, size_t ws_size,
                              hipStream_t stream) {
    const float* hidden = (const float*)d_in[0]; // [64,512]
    const float* enc    = (const float*)d_in[1]; // [64,1000,1024]
    const float* attn_w = (const float*)d_in[2]; // [1536,512]
    const float* attn_b = (const float*)d_in[3]; // [512]
    const float* v      = (const float*)d_in[4]; // [512]
    float* out = (float*)d_out;                  // [64,1000]

    char* ws = (char*)d_ws;
    unsigned short* Wt = (unsigned short*)ws;                       // 1 MB bf16
    float* hb  = (float*)(ws + (1 << 20));                          // 128 KB
    float* att = (float*)(ws + (1 << 20) + (128 << 10));            // 250 KB

    k_transpose<<<256, 256, 0, stream>>>(attn_w, Wt);
    k_hb<<<64, 512, 0, stream>>>(hidden, attn_w, attn_b, hb);
    k_main<<<dim3(16, 64), 256, 0, stream>>>(enc, Wt, hb, v, att);
    k_softmax<<<64, 256, 0, stream>>>(att, out);
}